// Round 9
// baseline (523.298 us; speedup 1.0000x reference)
//
#include <hip/hip_runtime.h>
#include <math.h>

typedef unsigned short u16;
typedef unsigned int u32;
typedef __attribute__((ext_vector_type(4))) float f32x4;
typedef __attribute__((ext_vector_type(8))) unsigned short u16x8;
typedef __attribute__((ext_vector_type(4))) unsigned short u16x4;
typedef __attribute__((ext_vector_type(8))) __bf16 bf16x8;

#define DEV __device__ __forceinline__

constexpr int S = 2048;
constexpr int HIDDEN = 5120;
constexpr int H = 16;
constexpr int NOPE = 128, ROPE_D = 64, VD = 128;
constexpr int QKD = NOPE + ROPE_D;  // 192
constexpr int QLORA = 1536, KVLORA = 512;
constexpr int KVA_N = KVLORA + ROPE_D;  // 576
constexpr float SCALING = 0.11472134f;

DEV u16 f2b(float f) {
  u32 u = __builtin_bit_cast(u32, f);
  u32 r = u + 0x7FFFu + ((u >> 16) & 1u);
  return (u16)(r >> 16);
}
DEV float b2f(u16 h) { return __builtin_bit_cast(float, (u32)h << 16); }

DEV void store_out(float* p, float v) { *p = v; }
DEV void store_out(u16* p, float v) { *p = f2b(v); }

DEV void gload_lds16(const u16* g, u16* l) {
  auto* gp = (const __attribute__((address_space(1))) u16*)g;
  auto* lp = (__attribute__((address_space(3))) u16*)l;
  __builtin_amdgcn_global_load_lds(gp, lp, 16, 0, 0);
}

#define SWZ(row, col) ((col) ^ (((row) & 7) << 3))

// ================= fused prep: convert + 4 transposes + rope tables ========
DEV void transpose_tile(const float* __restrict__ in, u16* __restrict__ out,
                        int R, int C, int c0, int r0, int tid, float (*tl)[33]) {
  int tx = tid & 31, ty = tid >> 5;
  for (int r = ty; r < 32; r += 8)
    tl[r][tx] = in[(size_t)(r0 + r) * C + c0 + tx];
  __syncthreads();
  for (int r = ty; r < 32; r += 8)
    out[(size_t)(c0 + r) * R + r0 + tx] = f2b(tl[tx][r]);
}

__global__ __launch_bounds__(256) void k_prep(const float* __restrict__ hidden, u16* __restrict__ hs_bf,
                                              const float* __restrict__ w_q_a, u16* __restrict__ bt_qa,
                                              const float* __restrict__ w_kv_a, u16* __restrict__ bt_kva,
                                              const float* __restrict__ w_q_b, u16* __restrict__ bt_qb,
                                              const float* __restrict__ w_kv_b, u16* __restrict__ bt_kvb,
                                              float* __restrict__ cs, float* __restrict__ sn) {
  __shared__ float tl[32][33];
  int b = blockIdx.x, tid = threadIdx.x;
  if (b < 10240) {  // convert
    int i = (b * 256 + tid) * 4;
    f32x4 v = *reinterpret_cast<const f32x4*>(hidden + i);
    u16x4 o;
    o[0] = f2b(v[0]); o[1] = f2b(v[1]); o[2] = f2b(v[2]); o[3] = f2b(v[3]);
    *reinterpret_cast<u16x4*>(hs_bf + i) = o;
    return;
  }
  b -= 10240;
  if (b < 7680) {
    transpose_tile(w_q_a, bt_qa, HIDDEN, QLORA, (b % 48) * 32, (b / 48) * 32, tid, tl);
    return;
  }
  b -= 7680;
  if (b < 2880) {
    transpose_tile(w_kv_a, bt_kva, HIDDEN, KVA_N, (b % 18) * 32, (b / 18) * 32, tid, tl);
    return;
  }
  b -= 2880;
  if (b < 4608) {
    transpose_tile(w_q_b, bt_qb, QLORA, H * QKD, (b % 96) * 32, (b / 96) * 32, tid, tl);
    return;
  }
  b -= 4608;
  if (b < 2048) {
    transpose_tile(w_kv_b, bt_kvb, KVLORA, H * 256, (b % 128) * 32, (b / 128) * 32, tid, tl);
    return;
  }
  b -= 2048;  // rope tables, b < 256
  int idx = b * 256 + tid;
  int s = idx >> 5, j = idx & 31;
  double pf = pow(10000.0, (double)j / 32.0);
  double inv_extra = 1.0 / pf;
  double inv_interp = 1.0 / (40.0 * pf);
  double twopi = 6.283185307179586476925286766559;
  double lnb2 = 2.0 * log(10000.0);
  double lowd = floor(64.0 * log(4096.0 / (32.0 * twopi)) / lnb2);
  if (lowd < 0.0) lowd = 0.0;
  double highd = ceil(64.0 * log(4096.0 / twopi) / lnb2);
  if (highd > 63.0) highd = 63.0;
  double denom = highd - lowd;
  if (denom < 0.001) denom = 0.001;
  double ramp = ((double)j - lowd) / denom;
  ramp = ramp < 0.0 ? 0.0 : (ramp > 1.0 ? 1.0 : ramp);
  float invf = (float)(inv_interp * ramp + inv_extra * (1.0 - ramp));
  float fr = (float)s * invf;
  cs[idx] = cosf(fr);
  sn[idx] = sinf(fr);
}

// ================= bf16 GEMM core: 2-deep dbuf + counted vmcnt (R4-proven) ==
DEV void gemm_core(u16* Al, u16* Bl, const u16* __restrict__ A,
                   const u16* __restrict__ BT,
                   int Kstride, int Klen, int mbase, int nbase, f32x4 (*acc)[4]) {
  const int tid = threadIdx.x;
  const int lane = tid & 63, wave = tid >> 6;
  const int wr = wave >> 1, wc = wave & 1;
  const int lr = lane & 15, lk = lane >> 4;
  const int srow = wave * 32 + (lane >> 2);
  const int skoff = (((lane & 3) ^ ((lane >> 3) & 3))) * 8;  // source swizzle
  const int swlk8 = (lk ^ ((lr >> 1) & 3)) * 8;              // read swizzle
  const u16* aptr = A + (size_t)(mbase + srow) * Kstride + skoff;
  const u16* bptr = BT + (size_t)(nbase + srow) * Kstride + skoff;
  u16* alw = Al + wave * (32 * 32);
  u16* blw = Bl + wave * (32 * 32);

  auto STAGE = [&](int b, int kk) {
    gload_lds16(aptr + kk, alw + b * 4096);
    gload_lds16(aptr + (size_t)16 * Kstride + kk, alw + b * 4096 + 16 * 32);
    gload_lds16(bptr + kk, blw + b * 4096);
    gload_lds16(bptr + (size_t)16 * Kstride + kk, blw + b * 4096 + 16 * 32);
  };

#pragma unroll
  for (int mf = 0; mf < 4; ++mf)
#pragma unroll
    for (int nf = 0; nf < 4; ++nf) acc[mf][nf] = {0.f, 0.f, 0.f, 0.f};

  const int nt = Klen >> 5;
  STAGE(0, 0);
  STAGE(1, 32);
  for (int t = 0; t < nt; ++t) {
    const int cur = t & 1;
    if (t + 1 < nt)
      asm volatile("s_waitcnt vmcnt(4)" ::: "memory");
    else
      asm volatile("s_waitcnt vmcnt(0)" ::: "memory");
    __builtin_amdgcn_s_barrier();
    const u16* Ac = Al + cur * 4096;
    const u16* Bc = Bl + cur * 4096;
    bf16x8 af[4], bfr[4];
#pragma unroll
    for (int mf = 0; mf < 4; ++mf)
      af[mf] = *reinterpret_cast<const bf16x8*>(Ac + (wr * 64 + mf * 16 + lr) * 32 + swlk8);
#pragma unroll
    for (int nf = 0; nf < 4; ++nf)
      bfr[nf] = *reinterpret_cast<const bf16x8*>(Bc + (wc * 64 + nf * 16 + lr) * 32 + swlk8);
#pragma unroll
    for (int mf = 0; mf < 4; ++mf)
#pragma unroll
      for (int nf = 0; nf < 4; ++nf)
        acc[mf][nf] = __builtin_amdgcn_mfma_f32_16x16x32_bf16(af[mf], bfr[nf], acc[mf][nf], 0, 0, 0);
    __builtin_amdgcn_s_barrier();
    if (t + 2 < nt) STAGE(cur, (t + 2) * 32);
  }
}

template <typename OutT>
DEV void gemm_epilogue(f32x4 (*acc)[4], OutT* __restrict__ C, int N, int mbase, int nbase) {
  const int lane = threadIdx.x & 63, wave = threadIdx.x >> 6;
  const int wr = wave >> 1, wc = wave & 1;
  const int lr = lane & 15, lk = lane >> 4;
#pragma unroll
  for (int mf = 0; mf < 4; ++mf)
#pragma unroll
    for (int nf = 0; nf < 4; ++nf) {
      int col = nbase + wc * 64 + nf * 16 + lr;
      if (col < N) {
#pragma unroll
        for (int r = 0; r < 4; ++r) {
          int row = mbase + wr * 64 + mf * 16 + lk * 4 + r;
          store_out(&C[(size_t)row * N + col], acc[mf][nf][r]);
        }
      }
    }
}

// out-proj: flat 640 = 40 cols x 16 rows, row inner (XCD keeps its A rows in L2)
__global__ __launch_bounds__(256) void k_gemm_out(const u16* __restrict__ A,
                                                  const u16* __restrict__ BT,
                                                  float* __restrict__ C) {
  __shared__ u16 Al[2 * 128 * 32];
  __shared__ u16 Bl[2 * 128 * 32];
  int id = blockIdx.x;
  int row = id & 15, col = id >> 4;
  f32x4 acc[4][4];
  gemm_core(Al, Bl, A, BT, H * VD, H * VD, row * 128, col * 128, acc);
  gemm_epilogue(acc, C, HIDDEN, row * 128, col * 128);
}

// up-proj with fused epilogue: writes qf (+RoPE), kf-nope, vt directly.
// flat 896 = 56 cols x 16 rows, row inner; col<24 -> q, else kv.
__global__ __launch_bounds__(256) void k_gemm_up(const u16* __restrict__ Aq, const u16* __restrict__ Bq,
                                                 const u16* __restrict__ Akv, const u16* __restrict__ Bkv,
                                                 const float* __restrict__ cs, const float* __restrict__ sn,
                                                 u16* __restrict__ qf, u16* __restrict__ kf,
                                                 u16* __restrict__ vt) {
  __shared__ u16 Al[2 * 128 * 32];
  __shared__ u16 Bl[2 * 128 * 32];
  int id = blockIdx.x;
  int rowb = id & 15, col = id >> 4;  // col 0..55
  const int mbase = rowb * 128;
  const int lane = threadIdx.x & 63, wave = threadIdx.x >> 6;
  const int wr = wave >> 1, wc = wave & 1;
  const int lr = lane & 15, lk = lane >> 4;
  f32x4 acc[4][4];
  if (col < 24) {
    const int nbase = col * 128;
    gemm_core(Al, Bl, Aq, Bq, QLORA, QLORA, mbase, nbase, acc);
#pragma unroll
    for (int nf = 0; nf < 4; ++nf) {
      int colb = nbase + wc * 64 + nf * 16;        // frag-uniform
      int h = colb / 192;
      int db = colb - h * 192;
      size_t qoff = (size_t)h * S * QKD;
      if (db < NOPE) {
#pragma unroll
        for (int mf = 0; mf < 4; ++mf)
#pragma unroll
          for (int r = 0; r < 4; ++r) {
            int row = mbase + wr * 64 + mf * 16 + lk * 4 + r;
            qf[qoff + (size_t)row * QKD + db + lr] = f2b(acc[mf][nf][r]);
          }
      } else {  // rope cols: pair exchange via shfl_xor(1)
        int jj = (db - NOPE + lr) >> 1;
        bool odd = lr & 1;
#pragma unroll
        for (int mf = 0; mf < 4; ++mf)
#pragma unroll
          for (int r = 0; r < 4; ++r) {
            int row = mbase + wr * 64 + mf * 16 + lk * 4 + r;
            float val = acc[mf][nf][r];
            float part = __shfl_xor(val, 1);
            float c = cs[row * 32 + jj], s = sn[row * 32 + jj];
            float o = odd ? (val * c + part * s) : (val * c - part * s);
            qf[qoff + (size_t)row * QKD + db + lr] = f2b(o);
          }
      }
    }
  } else {
    const int nbase = (col - 24) * 128;
    gemm_core(Al, Bl, Akv, Bkv, KVLORA, KVLORA, mbase, nbase, acc);
#pragma unroll
    for (int nf = 0; nf < 4; ++nf) {
      int colb = nbase + wc * 64 + nf * 16;
      int h = colb >> 8;        // /256, frag-uniform
      int db = colb & 255;
      if (db < NOPE) {          // k_nope -> kf
        size_t koff = (size_t)h * S * QKD;
#pragma unroll
        for (int mf = 0; mf < 4; ++mf)
#pragma unroll
          for (int r = 0; r < 4; ++r) {
            int row = mbase + wr * 64 + mf * 16 + lk * 4 + r;
            kf[koff + (size_t)row * QKD + db + lr] = f2b(acc[mf][nf][r]);
          }
      } else {                  // v -> vt (free transpose: frag is col-major)
        int vtrow = h * VD + db - NOPE + lr;
#pragma unroll
        for (int mf = 0; mf < 4; ++mf) {
          int row0 = mbase + wr * 64 + mf * 16 + lk * 4;
          u16x4 pk;
          pk[0] = f2b(acc[mf][nf][0]); pk[1] = f2b(acc[mf][nf][1]);
          pk[2] = f2b(acc[mf][nf][2]); pk[3] = f2b(acc[mf][nf][3]);
          *reinterpret_cast<u16x4*>(&vt[(size_t)vtrow * S + row0]) = pk;
        }
      }
    }
  }
}

// down-proj, split-K=2: flat 544 = 2 splits x 17 cols x 16 rows, row inner.
__global__ __launch_bounds__(256) void k_gemm_dp(const u16* __restrict__ A,
                                                 const u16* __restrict__ Bq,
                                                 const u16* __restrict__ Bkv,
                                                 float* __restrict__ q0, float* __restrict__ q1,
                                                 float* __restrict__ l0, float* __restrict__ l1) {
  __shared__ u16 Al[2 * 128 * 32];
  __shared__ u16 Bl[2 * 128 * 32];
  constexpr int KH = HIDDEN / 2;  // 2560
  int id = blockIdx.x;
  int split = id >= 272;
  int u = id - split * 272;
  int row = u & 15, colt = u >> 4;  // colt 0..16
  const u16* As = A + split * KH;
  f32x4 acc[4][4];
  if (colt < 12) {
    gemm_core(Al, Bl, As, Bq + split * KH, HIDDEN, KH, row * 128, colt * 128, acc);
    gemm_epilogue(acc, split ? q1 : q0, QLORA, row * 128, colt * 128);
  } else {
    gemm_core(Al, Bl, As, Bkv + split * KH, HIDDEN, KH, row * 128, (colt - 12) * 128, acc);
    gemm_epilogue(acc, split ? l1 : l0, KVA_N, row * 128, (colt - 12) * 128);
  }
}

// ====== fused mid: 2x rmsnorm(split-K reduce) + w_o transpose + kf-rope =====
DEV void rmsnorm2_row(const float* __restrict__ x0, const float* __restrict__ x1,
                      const float* __restrict__ w, u16* __restrict__ y,
                      int ncols, int instride, int row, int tid, float* red) {
  const float* xr0 = x0 + (size_t)row * instride;
  const float* xr1 = x1 + (size_t)row * instride;
  float ss = 0.f;
  for (int i = tid * 4; i < ncols; i += 1024) {
    f32x4 a = *reinterpret_cast<const f32x4*>(xr0 + i);
    f32x4 b = *reinterpret_cast<const f32x4*>(xr1 + i);
    f32x4 v = a + b;
    ss += v[0] * v[0] + v[1] * v[1] + v[2] * v[2] + v[3] * v[3];
  }
  for (int off = 32; off > 0; off >>= 1) ss += __shfl_down(ss, off);
  if ((tid & 63) == 0) red[tid >> 6] = ss;
  __syncthreads();
  ss = red[0] + red[1] + red[2] + red[3];
  float sc = rsqrtf(ss / (float)ncols + 1e-6f);
  u16* yr = y + (size_t)row * ncols;
  for (int i = tid * 4; i < ncols; i += 1024) {
    f32x4 a = *reinterpret_cast<const f32x4*>(xr0 + i);
    f32x4 b = *reinterpret_cast<const f32x4*>(xr1 + i);
    f32x4 v = a + b;
    u16x4 o;
    o[0] = f2b(v[0] * sc * w[i]);
    o[1] = f2b(v[1] * sc * w[i + 1]);
    o[2] = f2b(v[2] * sc * w[i + 2]);
    o[3] = f2b(v[3] * sc * w[i + 3]);
    *reinterpret_cast<u16x4*>(yr + i) = o;
  }
}

__global__ __launch_bounds__(256) void k_mid(const float* __restrict__ q0, const float* __restrict__ q1,
                                             const float* __restrict__ qw, u16* __restrict__ q_ln,
                                             const float* __restrict__ l0, const float* __restrict__ l1,
                                             const float* __restrict__ kw, u16* __restrict__ kv_ln,
                                             const float* __restrict__ w_o, u16* __restrict__ bt_o,
                                             const float* __restrict__ cs, const float* __restrict__ sn,
                                             u16* __restrict__ kf) {
  __shared__ float red[4];
  __shared__ float tl[32][33];
  int b = blockIdx.x, tid = threadIdx.x;
  if (b < 2048) {
    rmsnorm2_row(q0, q1, qw, q_ln, QLORA, QLORA, b, tid, red);
    return;
  }
  if (b < 4096) {
    rmsnorm2_row(l0, l1, kw, kv_ln, KVLORA, KVA_N, b - 2048, tid, red);
    return;
  }
  if (b < 14336) {
    int u = b - 4096;  // w_o transpose: R=2048, C=5120, 160x64 tiles
    transpose_tile(w_o, bt_o, H * VD, HIDDEN, (u % 160) * 32, (u / 160) * 32, tid, tl);
    return;
  }
  // kf-rope: k_pe from latent, broadcast to all heads.  b in [14336, 16384)
  int s = b - 14336;
  for (int idx = tid; idx < H * 32; idx += 256) {
    int h = idx >> 5, j = idx & 31;
    float c = cs[s * 32 + j], si = sn[s * 32 + j];
    float k1 = l0[(size_t)s * KVA_N + KVLORA + 2 * j] + l1[(size_t)s * KVA_N + KVLORA + 2 * j];
    float k2 = l0[(size_t)s * KVA_N + KVLORA + 2 * j + 1] + l1[(size_t)s * KVA_N + KVLORA + 2 * j + 1];
    kf[((size_t)h * S + s) * QKD + NOPE + 2 * j] = f2b(k1 * c - k2 * si);
    kf[((size_t)h * S + s) * QKD + NOPE + 2 * j + 1] = f2b(k2 * c + k1 * si);
  }
}

// ========= flash attention (causal): barrier-free, direct-L2 K/V ===========
// grid 512: h = bid&15 (XCD-pinned: all 32 blocks of head h on XCD h%8),
// qt = j<16 ? j : 47-j  (bid and bid+256 form a balanced qt pair per CU).
__global__ __launch_bounds__(256) void k_attn(const u16* __restrict__ qf,
                                              const u16* __restrict__ kf,
                                              const u16* __restrict__ vt,
                                              u16* __restrict__ attn) {
  const int bid = blockIdx.x;
  const int h = bid & 15;
  const int j = bid >> 4;
  const int qt = (j < 16) ? j : 47 - j;
  const int qbase = qt * 64;
  const int tid = threadIdx.x, wave = tid >> 6, lane = tid & 63;
  const int lr = lane & 15, lk = lane >> 4;
  __shared__ u16 Pl[4][16][64];  // wave-private: no barriers anywhere

  const u16* kfh = kf + (size_t)h * S * QKD;
  const u16* vth = vt + (size_t)h * VD * S;

  bf16x8 qfrag[6];
  const u16* qrow = qf + ((size_t)h * S + qbase + wave * 16 + lr) * QKD;
#pragma unroll
  for (int d = 0; d < 6; ++d)
    qfrag[d] = *reinterpret_cast<const bf16x8*>(qrow + d * 32 + lk * 8);

  f32x4 o[8];
#pragma unroll
  for (int f = 0; f < 8; ++f) o[f] = {0.f, 0.f, 0.f, 0.f};
  float m_[4] = {-__builtin_inff(), -__builtin_inff(), -__builtin_inff(), -__builtin_inff()};
  float l_[4] = {0.f, 0.f, 0.f, 0.f};

  const int ktiles = qt + 1;
  for (int kt = 0; kt < ktiles; ++kt) {
    const int kbase = kt * 64;

    // QK^T: B-frags straight from global (L2-resident per-XCD)
    f32x4 sacc[4];
#pragma unroll
    for (int nf = 0; nf < 4; ++nf) sacc[nf] = {0.f, 0.f, 0.f, 0.f};
    __builtin_amdgcn_s_setprio(1);
#pragma unroll
    for (int nf = 0; nf < 4; ++nf) {
      const u16* kp = kfh + (size_t)(kbase + nf * 16 + lr) * QKD + lk * 8;
#pragma unroll
      for (int dk = 0; dk < 6; ++dk) {
        bf16x8 b = *reinterpret_cast<const bf16x8*>(kp + dk * 32);
        sacc[nf] = __builtin_amdgcn_mfma_f32_16x16x32_bf16(qfrag[dk], b, sacc[nf], 0, 0, 0);
      }
    }
    __builtin_amdgcn_s_setprio(0);

    float sv[4][4];
    float rowmax[4] = {-__builtin_inff(), -__builtin_inff(), -__builtin_inff(), -__builtin_inff()};
#pragma unroll
    for (int nf = 0; nf < 4; ++nf) {
      int kcol = kbase + nf * 16 + lr;
#pragma unroll
      for (int r = 0; r < 4; ++r) {
        float v = sacc[nf][r] * SCALING;
        int qrow_g = qbase + wave * 16 + lk * 4 + r;
        if (kcol > qrow_g) v = -__builtin_inff();
        sv[nf][r] = v;
        rowmax[r] = fmaxf(rowmax[r], v);
      }
    }
#pragma unroll
    for (int r = 0; r < 4; ++r) {
#pragma unroll
      for (int off = 1; off < 16; off <<= 1)
        rowmax[r] = fmaxf(rowmax[r], __shfl_xor(rowmax[r], off));
    }
    // T13 defer-max: skip rescale while per-tile max growth <= 8
    float needm = fmaxf(fmaxf(rowmax[0] - m_[0], rowmax[1] - m_[1]),
                        fmaxf(rowmax[2] - m_[2], rowmax[3] - m_[3]));
    if (!__all(needm <= 8.0f)) {
#pragma unroll
      for (int r = 0; r < 4; ++r) {
        float mn = fmaxf(m_[r], rowmax[r]);
        float alpha = __expf(m_[r] - mn);
        m_[r] = mn;
        l_[r] *= alpha;
#pragma unroll
        for (int f = 0; f < 8; ++f) o[f][r] *= alpha;
      }
    }
    float rowsum[4] = {0.f, 0.f, 0.f, 0.f};
#pragma unroll
    for (int nf = 0; nf < 4; ++nf)
#pragma unroll
      for (int r = 0; r < 4; ++r) {
        float p = __expf(sv[nf][r] - m_[r]);
        sv[nf][r] = p;
        rowsum[r] += p;
      }
#pragma unroll
    for (int r = 0; r < 4; ++r) {
#pragma unroll
      for (int off = 1; off < 16; off <<= 1) rowsum[r] += __shfl_xor(rowsum[r], off);
      l_[r] += rowsum[r];
    }
#pragma unroll
    for (int nf = 0; nf < 4; ++nf)
#pragma unroll
      for (int r = 0; r < 4; ++r) {
        int prow = lk * 4 + r;
        Pl[wave][prow][SWZ(prow, nf * 16 + lr)] = f2b(sv[nf][r]);
      }
    // (compiler inserts lgkmcnt wait for Pl write->read; wave-private, no barrier)

    // PV: V B-frags straight from global
    __builtin_amdgcn_s_setprio(1);
#pragma unroll
    for (int kk = 0; kk < 2; ++kk) {
      bf16x8 pa = *reinterpret_cast<const bf16x8*>(&Pl[wave][lr][SWZ(lr, kk * 32 + lk * 8)]);
#pragma unroll
      for (int f = 0; f < 8; ++f) {
        const u16* vp = vth + (size_t)(f * 16 + lr) * S + kbase + kk * 32 + lk * 8;
        bf16x8 b = *reinterpret_cast<const bf16x8*>(vp);
        o[f] = __builtin_amdgcn_mfma_f32_16x16x32_bf16(pa, b, o[f], 0, 0, 0);
      }
    }
    __builtin_amdgcn_s_setprio(0);
  }

#pragma unroll
  for (int f = 0; f < 8; ++f)
#pragma unroll
    for (int r = 0; r < 4; ++r) {
      int row = qbase + wave * 16 + lk * 4 + r;
      float val = o[f][r] / l_[r];
      attn[(size_t)row * (H * VD) + h * VD + f * 16 + lr] = f2b(val);
    }
}

// ---------------- host launch ----------------
extern "C" void kernel_launch(void* const* d_in, const int* in_sizes, int n_in,
                              void* d_out, int out_size, void* d_ws, size_t ws_size,
                              hipStream_t stream) {
  (void)in_sizes; (void)n_in; (void)out_size; (void)ws_size;
  const float* hidden    = (const float*)d_in[1];
  const float* w_q_a     = (const float*)d_in[2];
  const float* q_a_ln_w  = (const float*)d_in[3];
  const float* w_q_b     = (const float*)d_in[4];
  const float* w_kv_a    = (const float*)d_in[5];
  const float* kv_a_ln_w = (const float*)d_in[6];
  const float* w_kv_b    = (const float*)d_in[7];
  const float* w_o       = (const float*)d_in[8];
  float* out = (float*)d_out;

  char* ws = (char*)d_ws;
  size_t off = 0;
  auto alloc = [&](size_t bytes) {
    size_t o = off;
    off += (bytes + 255) & ~(size_t)255;
    return o;
  };
  constexpr int KVA_PAD = 640;  // 576 padded to multiple of 128 (unguarded DMA)
  size_t o_hs    = alloc((size_t)S * HIDDEN * 2);        // hs bf16; later reused as qf
  size_t o_btqa  = alloc((size_t)QLORA * HIDDEN * 2);    // later (with o_btkva) bt_o
  size_t o_btkva = alloc((size_t)KVA_PAD * HIDDEN * 2);
  size_t o_btqb  = alloc((size_t)(H * QKD) * QLORA * 2);
  size_t o_btkvb = alloc((size_t)(H * 256) * KVLORA * 2);
  size_t o_qlat0 = alloc((size_t)S * QLORA * 4);         // later reused as attn
  size_t o_qlat1 = alloc((size_t)S * QLORA * 4);
  size_t o_lat0  = alloc((size_t)S * KVA_N * 4);
  size_t o_lat1  = alloc((size_t)S * KVA_N * 4);
  size_t o_qln   = alloc((size_t)S * QLORA * 2);
  size_t o_kvln  = alloc((size_t)S * KVLORA * 2);
  size_t o_kf    = alloc((size_t)H * S * QKD * 2);
  size_t o_vt    = alloc((size_t)H * VD * S * 2);
  size_t o_cs    = alloc((size_t)S * 32 * 4);
  size_t o_sn    = alloc((size_t)S * 32 * 4);

  u16* hs_bf  = (u16*)(ws + o_hs);
  u16* bt_qa  = (u16*)(ws + o_btqa);
  u16* bt_kva = (u16*)(ws + o_btkva);
  u16* bt_qb  = (u16*)(ws + o_btqb);
  u16* bt_kvb = (u16*)(ws + o_btkvb);
  float* q_lat0 = (float*)(ws + o_qlat0);
  float* q_lat1 = (float*)(ws + o_qlat1);
  float* lat0   = (float*)(ws + o_lat0);
  float* lat1   = (float*)(ws + o_lat1);
  u16* q_ln  = (u16*)(ws + o_qln);
  u16* kv_ln = (u16*)(ws + o_kvln);
  u16* kf    = (u16*)(ws + o_kf);
  u16* vt    = (u16*)(ws + o_vt);
  float* cs = (float*)(ws + o_cs);
  float* sn = (float*)(ws + o_sn);
  // aliases (lifetimes verified: source buffers dead before alias written)
  u16* qf   = (u16*)(ws + o_hs);    // hs_bf dead after dp
  u16* bt_o = (u16*)(ws + o_btqa);  // spans btqa+btkva, dead after dp
  u16* attn = (u16*)(ws + o_qlat0); // q_lat0 dead after mid

  // 1. fused prep: convert + 4 weight transposes + rope tables (27712 blocks)
  k_prep<<<dim3(27712), dim3(256), 0, stream>>>(hidden, hs_bf, w_q_a, bt_qa,
                                                w_kv_a, bt_kva, w_q_b, bt_qb,
                                                w_kv_b, bt_kvb, cs, sn);

  // 2. down-projections: split-K=2, flat 544, row-inner mapping (L2 pinning)
  k_gemm_dp<<<dim3(544), dim3(256), 0, stream>>>(hs_bf, bt_qa, bt_kva,
                                                 q_lat0, q_lat1, lat0, lat1);

  // 3. fused mid: rmsnorms + w_o transpose + kf-rope (16384 blocks)
  k_mid<<<dim3(16384), dim3(256), 0, stream>>>(q_lat0, q_lat1, q_a_ln_w, q_ln,
                                               lat0, lat1, kv_a_ln_w, kv_ln,
                                               w_o, bt_o, cs, sn, kf);

  // 4. up-projections with fused build epilogue: flat 896, row-inner mapping
  k_gemm_up<<<dim3(896), dim3(256), 0, stream>>>(q_ln, bt_qb, kv_ln, bt_kvb,
                                                 cs, sn, qf, kf, vt);

  // 5. attention: barrier-free, head->XCD pinned (512 blocks)
  k_attn<<<dim3(512), dim3(256), 0, stream>>>(qf, kf, vt, attn);

  // 6. output projection: flat 640, row-inner mapping
  k_gemm_out<<<dim3(640), dim3(256), 0, stream>>>(attn, bt_o, out);
}

// Round 10
// 315.274 us; speedup vs baseline: 1.6598x; 1.6598x over previous
//
#include <hip/hip_runtime.h>
#include <math.h>

typedef unsigned short u16;
typedef unsigned int u32;
typedef __attribute__((ext_vector_type(4))) float f32x4;
typedef __attribute__((ext_vector_type(8))) unsigned short u16x8;
typedef __attribute__((ext_vector_type(4))) unsigned short u16x4;
typedef __attribute__((ext_vector_type(8))) __bf16 bf16x8;

#define DEV __device__ __forceinline__

constexpr int S = 2048;
constexpr int HIDDEN = 5120;
constexpr int H = 16;
constexpr int NOPE = 128, ROPE_D = 64, VD = 128;
constexpr int QKD = NOPE + ROPE_D;  // 192
constexpr int QLORA = 1536, KVLORA = 512;
constexpr int KVA_N = KVLORA + ROPE_D;  // 576
constexpr float SCALING = 0.11472134f;

DEV u16 f2b(float f) {
  u32 u = __builtin_bit_cast(u32, f);
  u32 r = u + 0x7FFFu + ((u >> 16) & 1u);
  return (u16)(r >> 16);
}
DEV float b2f(u16 h) { return __builtin_bit_cast(float, (u32)h << 16); }

DEV void store_out(float* p, float v) { *p = v; }
DEV void store_out(u16* p, float v) { *p = f2b(v); }

DEV void gload_lds16(const u16* g, u16* l) {
  auto* gp = (const __attribute__((address_space(1))) u16*)g;
  auto* lp = (__attribute__((address_space(3))) u16*)l;
  __builtin_amdgcn_global_load_lds(gp, lp, 16, 0, 0);
}

#define SWZ(row, col) ((col) ^ (((row) & 7) << 3))

// ================= fused prep: convert + 4 transposes + rope tables ========
DEV void transpose_tile(const float* __restrict__ in, u16* __restrict__ out,
                        int R, int C, int c0, int r0, int tid, float (*tl)[33]) {
  int tx = tid & 31, ty = tid >> 5;
  for (int r = ty; r < 32; r += 8)
    tl[r][tx] = in[(size_t)(r0 + r) * C + c0 + tx];
  __syncthreads();
  for (int r = ty; r < 32; r += 8)
    out[(size_t)(c0 + r) * R + r0 + tx] = f2b(tl[tx][r]);
}

__global__ __launch_bounds__(256) void k_prep(const float* __restrict__ hidden, u16* __restrict__ hs_bf,
                                              const float* __restrict__ w_q_a, u16* __restrict__ bt_qa,
                                              const float* __restrict__ w_kv_a, u16* __restrict__ bt_kva,
                                              const float* __restrict__ w_q_b, u16* __restrict__ bt_qb,
                                              const float* __restrict__ w_kv_b, u16* __restrict__ bt_kvb,
                                              float* __restrict__ cs, float* __restrict__ sn) {
  __shared__ float tl[32][33];
  int b = blockIdx.x, tid = threadIdx.x;
  if (b < 10240) {  // convert
    int i = (b * 256 + tid) * 4;
    f32x4 v = *reinterpret_cast<const f32x4*>(hidden + i);
    u16x4 o;
    o[0] = f2b(v[0]); o[1] = f2b(v[1]); o[2] = f2b(v[2]); o[3] = f2b(v[3]);
    *reinterpret_cast<u16x4*>(hs_bf + i) = o;
    return;
  }
  b -= 10240;
  if (b < 7680) {
    transpose_tile(w_q_a, bt_qa, HIDDEN, QLORA, (b % 48) * 32, (b / 48) * 32, tid, tl);
    return;
  }
  b -= 7680;
  if (b < 2880) {
    transpose_tile(w_kv_a, bt_kva, HIDDEN, KVA_N, (b % 18) * 32, (b / 18) * 32, tid, tl);
    return;
  }
  b -= 2880;
  if (b < 4608) {
    transpose_tile(w_q_b, bt_qb, QLORA, H * QKD, (b % 96) * 32, (b / 96) * 32, tid, tl);
    return;
  }
  b -= 4608;
  if (b < 2048) {
    transpose_tile(w_kv_b, bt_kvb, KVLORA, H * 256, (b % 128) * 32, (b / 128) * 32, tid, tl);
    return;
  }
  b -= 2048;  // rope tables, b < 256
  int idx = b * 256 + tid;
  int s = idx >> 5, j = idx & 31;
  double pf = pow(10000.0, (double)j / 32.0);
  double inv_extra = 1.0 / pf;
  double inv_interp = 1.0 / (40.0 * pf);
  double twopi = 6.283185307179586476925286766559;
  double lnb2 = 2.0 * log(10000.0);
  double lowd = floor(64.0 * log(4096.0 / (32.0 * twopi)) / lnb2);
  if (lowd < 0.0) lowd = 0.0;
  double highd = ceil(64.0 * log(4096.0 / twopi) / lnb2);
  if (highd > 63.0) highd = 63.0;
  double denom = highd - lowd;
  if (denom < 0.001) denom = 0.001;
  double ramp = ((double)j - lowd) / denom;
  ramp = ramp < 0.0 ? 0.0 : (ramp > 1.0 ? 1.0 : ramp);
  float invf = (float)(inv_interp * ramp + inv_extra * (1.0 - ramp));
  float fr = (float)s * invf;
  cs[idx] = cosf(fr);
  sn[idx] = sinf(fr);
}

// ================= bf16 GEMM core: 2-deep dbuf + counted vmcnt (R4-proven) ==
DEV void gemm_core(u16* Al, u16* Bl, const u16* __restrict__ A,
                   const u16* __restrict__ BT,
                   int Kstride, int Klen, int mbase, int nbase, f32x4 (*acc)[4]) {
  const int tid = threadIdx.x;
  const int lane = tid & 63, wave = tid >> 6;
  const int wr = wave >> 1, wc = wave & 1;
  const int lr = lane & 15, lk = lane >> 4;
  const int srow = wave * 32 + (lane >> 2);
  const int skoff = (((lane & 3) ^ ((lane >> 3) & 3))) * 8;  // source swizzle
  const int swlk8 = (lk ^ ((lr >> 1) & 3)) * 8;              // read swizzle
  const u16* aptr = A + (size_t)(mbase + srow) * Kstride + skoff;
  const u16* bptr = BT + (size_t)(nbase + srow) * Kstride + skoff;
  u16* alw = Al + wave * (32 * 32);
  u16* blw = Bl + wave * (32 * 32);

  auto STAGE = [&](int b, int kk) {
    gload_lds16(aptr + kk, alw + b * 4096);
    gload_lds16(aptr + (size_t)16 * Kstride + kk, alw + b * 4096 + 16 * 32);
    gload_lds16(bptr + kk, blw + b * 4096);
    gload_lds16(bptr + (size_t)16 * Kstride + kk, blw + b * 4096 + 16 * 32);
  };

#pragma unroll
  for (int mf = 0; mf < 4; ++mf)
#pragma unroll
    for (int nf = 0; nf < 4; ++nf) acc[mf][nf] = {0.f, 0.f, 0.f, 0.f};

  const int nt = Klen >> 5;
  STAGE(0, 0);
  STAGE(1, 32);
  for (int t = 0; t < nt; ++t) {
    const int cur = t & 1;
    if (t + 1 < nt)
      asm volatile("s_waitcnt vmcnt(4)" ::: "memory");
    else
      asm volatile("s_waitcnt vmcnt(0)" ::: "memory");
    __builtin_amdgcn_s_barrier();
    const u16* Ac = Al + cur * 4096;
    const u16* Bc = Bl + cur * 4096;
    bf16x8 af[4], bfr[4];
#pragma unroll
    for (int mf = 0; mf < 4; ++mf)
      af[mf] = *reinterpret_cast<const bf16x8*>(Ac + (wr * 64 + mf * 16 + lr) * 32 + swlk8);
#pragma unroll
    for (int nf = 0; nf < 4; ++nf)
      bfr[nf] = *reinterpret_cast<const bf16x8*>(Bc + (wc * 64 + nf * 16 + lr) * 32 + swlk8);
#pragma unroll
    for (int mf = 0; mf < 4; ++mf)
#pragma unroll
      for (int nf = 0; nf < 4; ++nf)
        acc[mf][nf] = __builtin_amdgcn_mfma_f32_16x16x32_bf16(af[mf], bfr[nf], acc[mf][nf], 0, 0, 0);
    __builtin_amdgcn_s_barrier();
    if (t + 2 < nt) STAGE(cur, (t + 2) * 32);
  }
}

template <typename OutT>
DEV void gemm_epilogue(f32x4 (*acc)[4], OutT* __restrict__ C, int N, int mbase, int nbase) {
  const int lane = threadIdx.x & 63, wave = threadIdx.x >> 6;
  const int wr = wave >> 1, wc = wave & 1;
  const int lr = lane & 15, lk = lane >> 4;
#pragma unroll
  for (int mf = 0; mf < 4; ++mf)
#pragma unroll
    for (int nf = 0; nf < 4; ++nf) {
      int col = nbase + wc * 64 + nf * 16 + lr;
      if (col < N) {
#pragma unroll
        for (int r = 0; r < 4; ++r) {
          int row = mbase + wr * 64 + mf * 16 + lk * 4 + r;
          store_out(&C[(size_t)row * N + col], acc[mf][nf][r]);
        }
      }
    }
}

// out-proj: flat 640 = 40 cols x 16 rows, row inner (XCD keeps its A rows in L2)
__global__ __launch_bounds__(256) void k_gemm_out(const u16* __restrict__ A,
                                                  const u16* __restrict__ BT,
                                                  float* __restrict__ C) {
  __shared__ u16 Al[2 * 128 * 32];
  __shared__ u16 Bl[2 * 128 * 32];
  int id = blockIdx.x;
  int row = id & 15, col = id >> 4;
  f32x4 acc[4][4];
  gemm_core(Al, Bl, A, BT, H * VD, H * VD, row * 128, col * 128, acc);
  gemm_epilogue(acc, C, HIDDEN, row * 128, col * 128);
}

// up-proj with fused epilogue: writes qf (+RoPE), kf-nope, vt directly.
// flat 896 = 56 cols x 16 rows, row inner; col<24 -> q, else kv.
__global__ __launch_bounds__(256) void k_gemm_up(const u16* __restrict__ Aq, const u16* __restrict__ Bq,
                                                 const u16* __restrict__ Akv, const u16* __restrict__ Bkv,
                                                 const float* __restrict__ cs, const float* __restrict__ sn,
                                                 u16* __restrict__ qf, u16* __restrict__ kf,
                                                 u16* __restrict__ vt) {
  __shared__ u16 Al[2 * 128 * 32];
  __shared__ u16 Bl[2 * 128 * 32];
  int id = blockIdx.x;
  int rowb = id & 15, col = id >> 4;  // col 0..55
  const int mbase = rowb * 128;
  const int lane = threadIdx.x & 63, wave = threadIdx.x >> 6;
  const int wr = wave >> 1, wc = wave & 1;
  const int lr = lane & 15, lk = lane >> 4;
  f32x4 acc[4][4];
  if (col < 24) {
    const int nbase = col * 128;
    gemm_core(Al, Bl, Aq, Bq, QLORA, QLORA, mbase, nbase, acc);
#pragma unroll
    for (int nf = 0; nf < 4; ++nf) {
      int colb = nbase + wc * 64 + nf * 16;        // frag-uniform
      int h = colb / 192;
      int db = colb - h * 192;
      size_t qoff = (size_t)h * S * QKD;
      if (db < NOPE) {
#pragma unroll
        for (int mf = 0; mf < 4; ++mf)
#pragma unroll
          for (int r = 0; r < 4; ++r) {
            int row = mbase + wr * 64 + mf * 16 + lk * 4 + r;
            qf[qoff + (size_t)row * QKD + db + lr] = f2b(acc[mf][nf][r]);
          }
      } else {  // rope cols: pair exchange via shfl_xor(1)
        int jj = (db - NOPE + lr) >> 1;
        bool odd = lr & 1;
#pragma unroll
        for (int mf = 0; mf < 4; ++mf)
#pragma unroll
          for (int r = 0; r < 4; ++r) {
            int row = mbase + wr * 64 + mf * 16 + lk * 4 + r;
            float val = acc[mf][nf][r];
            float part = __shfl_xor(val, 1);
            float c = cs[row * 32 + jj], s = sn[row * 32 + jj];
            float o = odd ? (val * c + part * s) : (val * c - part * s);
            qf[qoff + (size_t)row * QKD + db + lr] = f2b(o);
          }
      }
    }
  } else {
    const int nbase = (col - 24) * 128;
    gemm_core(Al, Bl, Akv, Bkv, KVLORA, KVLORA, mbase, nbase, acc);
#pragma unroll
    for (int nf = 0; nf < 4; ++nf) {
      int colb = nbase + wc * 64 + nf * 16;
      int h = colb >> 8;        // /256, frag-uniform
      int db = colb & 255;
      if (db < NOPE) {          // k_nope -> kf
        size_t koff = (size_t)h * S * QKD;
#pragma unroll
        for (int mf = 0; mf < 4; ++mf)
#pragma unroll
          for (int r = 0; r < 4; ++r) {
            int row = mbase + wr * 64 + mf * 16 + lk * 4 + r;
            kf[koff + (size_t)row * QKD + db + lr] = f2b(acc[mf][nf][r]);
          }
      } else {                  // v -> vt (free transpose: frag is col-major)
        int vtrow = h * VD + db - NOPE + lr;
#pragma unroll
        for (int mf = 0; mf < 4; ++mf) {
          int row0 = mbase + wr * 64 + mf * 16 + lk * 4;
          u16x4 pk;
          pk[0] = f2b(acc[mf][nf][0]); pk[1] = f2b(acc[mf][nf][1]);
          pk[2] = f2b(acc[mf][nf][2]); pk[3] = f2b(acc[mf][nf][3]);
          *reinterpret_cast<u16x4*>(&vt[(size_t)vtrow * S + row0]) = pk;
        }
      }
    }
  }
}

// down-proj, split-K=2: flat 544 = 2 splits x 17 cols x 16 rows, row inner.
__global__ __launch_bounds__(256) void k_gemm_dp(const u16* __restrict__ A,
                                                 const u16* __restrict__ Bq,
                                                 const u16* __restrict__ Bkv,
                                                 float* __restrict__ q0, float* __restrict__ q1,
                                                 float* __restrict__ l0, float* __restrict__ l1) {
  __shared__ u16 Al[2 * 128 * 32];
  __shared__ u16 Bl[2 * 128 * 32];
  constexpr int KH = HIDDEN / 2;  // 2560
  int id = blockIdx.x;
  int split = id >= 272;
  int u = id - split * 272;
  int row = u & 15, colt = u >> 4;  // colt 0..16
  const u16* As = A + split * KH;
  f32x4 acc[4][4];
  if (colt < 12) {
    gemm_core(Al, Bl, As, Bq + split * KH, HIDDEN, KH, row * 128, colt * 128, acc);
    gemm_epilogue(acc, split ? q1 : q0, QLORA, row * 128, colt * 128);
  } else {
    gemm_core(Al, Bl, As, Bkv + split * KH, HIDDEN, KH, row * 128, (colt - 12) * 128, acc);
    gemm_epilogue(acc, split ? l1 : l0, KVA_N, row * 128, (colt - 12) * 128);
  }
}

// ====== fused mid: 2x rmsnorm(split-K reduce) + w_o transpose + kf-rope =====
DEV void rmsnorm2_row(const float* __restrict__ x0, const float* __restrict__ x1,
                      const float* __restrict__ w, u16* __restrict__ y,
                      int ncols, int instride, int row, int tid, float* red) {
  const float* xr0 = x0 + (size_t)row * instride;
  const float* xr1 = x1 + (size_t)row * instride;
  float ss = 0.f;
  for (int i = tid * 4; i < ncols; i += 1024) {
    f32x4 a = *reinterpret_cast<const f32x4*>(xr0 + i);
    f32x4 b = *reinterpret_cast<const f32x4*>(xr1 + i);
    f32x4 v = a + b;
    ss += v[0] * v[0] + v[1] * v[1] + v[2] * v[2] + v[3] * v[3];
  }
  for (int off = 32; off > 0; off >>= 1) ss += __shfl_down(ss, off);
  if ((tid & 63) == 0) red[tid >> 6] = ss;
  __syncthreads();
  ss = red[0] + red[1] + red[2] + red[3];
  float sc = rsqrtf(ss / (float)ncols + 1e-6f);
  u16* yr = y + (size_t)row * ncols;
  for (int i = tid * 4; i < ncols; i += 1024) {
    f32x4 a = *reinterpret_cast<const f32x4*>(xr0 + i);
    f32x4 b = *reinterpret_cast<const f32x4*>(xr1 + i);
    f32x4 v = a + b;
    u16x4 o;
    o[0] = f2b(v[0] * sc * w[i]);
    o[1] = f2b(v[1] * sc * w[i + 1]);
    o[2] = f2b(v[2] * sc * w[i + 2]);
    o[3] = f2b(v[3] * sc * w[i + 3]);
    *reinterpret_cast<u16x4*>(yr + i) = o;
  }
}

__global__ __launch_bounds__(256) void k_mid(const float* __restrict__ q0, const float* __restrict__ q1,
                                             const float* __restrict__ qw, u16* __restrict__ q_ln,
                                             const float* __restrict__ l0, const float* __restrict__ l1,
                                             const float* __restrict__ kw, u16* __restrict__ kv_ln,
                                             const float* __restrict__ w_o, u16* __restrict__ bt_o,
                                             const float* __restrict__ cs, const float* __restrict__ sn,
                                             u16* __restrict__ kf) {
  __shared__ float red[4];
  __shared__ float tl[32][33];
  int b = blockIdx.x, tid = threadIdx.x;
  if (b < 2048) {
    rmsnorm2_row(q0, q1, qw, q_ln, QLORA, QLORA, b, tid, red);
    return;
  }
  if (b < 4096) {
    rmsnorm2_row(l0, l1, kw, kv_ln, KVLORA, KVA_N, b - 2048, tid, red);
    return;
  }
  if (b < 14336) {
    int u = b - 4096;  // w_o transpose: R=2048, C=5120, 160x64 tiles
    transpose_tile(w_o, bt_o, H * VD, HIDDEN, (u % 160) * 32, (u / 160) * 32, tid, tl);
    return;
  }
  // kf-rope: k_pe from latent, broadcast to all heads.  b in [14336, 16384)
  int s = b - 14336;
  for (int idx = tid; idx < H * 32; idx += 256) {
    int h = idx >> 5, j = idx & 31;
    float c = cs[s * 32 + j], si = sn[s * 32 + j];
    float k1 = l0[(size_t)s * KVA_N + KVLORA + 2 * j] + l1[(size_t)s * KVA_N + KVLORA + 2 * j];
    float k2 = l0[(size_t)s * KVA_N + KVLORA + 2 * j + 1] + l1[(size_t)s * KVA_N + KVLORA + 2 * j + 1];
    kf[((size_t)h * S + s) * QKD + NOPE + 2 * j] = f2b(k1 * c - k2 * si);
    kf[((size_t)h * S + s) * QKD + NOPE + 2 * j + 1] = f2b(k2 * c + k1 * si);
  }
}

// ===== flash attention (causal), R8-proven staged version ===================
// grid 512 flat; blocks i and i+256 get complementary qt (work-balanced).
__global__ __launch_bounds__(256) void k_attn(const u16* __restrict__ qf,
                                              const u16* __restrict__ kf,
                                              const u16* __restrict__ vt,
                                              u16* __restrict__ attn) {
  const int bidx = blockIdx.x;
  const int j = bidx & 31;
  const int h = bidx >> 5;
  const int qt = (h < 8) ? j : 31 - j;
  const int qbase = qt * 64;
  const int tid = threadIdx.x, wave = tid >> 6, lane = tid & 63;
  const int lr = lane & 15, lk = lane >> 4;
  __shared__ u16 Kl[64][192];
  __shared__ u16 Vl[128][64];
  __shared__ u16 Pl[4][16][64];

  int krow_[6], kofs_[6], vrow_[4], vofs_[4];
#pragma unroll
  for (int i = 0; i < 6; ++i) { int c = tid + i * 256; krow_[i] = c / 24; kofs_[i] = (c % 24) * 8; }
#pragma unroll
  for (int i = 0; i < 4; ++i) { int c = tid + i * 256; vrow_[i] = c >> 3; vofs_[i] = (c & 7) * 8; }
  const u16* kfh = kf + (size_t)h * S * QKD;
  const u16* vth = vt + (size_t)h * VD * S;

  bf16x8 qfrag[6];
  const u16* qrow = qf + ((size_t)h * S + qbase + wave * 16 + lr) * QKD;
#pragma unroll
  for (int d = 0; d < 6; ++d)
    qfrag[d] = *reinterpret_cast<const bf16x8*>(qrow + d * 32 + lk * 8);

  u16x8 kreg[6], vreg[4];
#pragma unroll
  for (int i = 0; i < 6; ++i)
    kreg[i] = *reinterpret_cast<const u16x8*>(kfh + (size_t)krow_[i] * QKD + kofs_[i]);
#pragma unroll
  for (int i = 0; i < 4; ++i)
    vreg[i] = *reinterpret_cast<const u16x8*>(vth + (size_t)vrow_[i] * S + vofs_[i]);

  f32x4 o[8];
#pragma unroll
  for (int f = 0; f < 8; ++f) o[f] = {0.f, 0.f, 0.f, 0.f};
  float m_[4] = {-__builtin_inff(), -__builtin_inff(), -__builtin_inff(), -__builtin_inff()};
  float l_[4] = {0.f, 0.f, 0.f, 0.f};

  const int ktiles = qt + 1;
  for (int kt = 0; kt < ktiles; ++kt) {
    const int kbase = kt * 64;
    __builtin_amdgcn_s_barrier();
#pragma unroll
    for (int i = 0; i < 6; ++i)
      *reinterpret_cast<u16x8*>(&Kl[krow_[i]][SWZ(krow_[i], kofs_[i])]) = kreg[i];
#pragma unroll
    for (int i = 0; i < 4; ++i)
      *reinterpret_cast<u16x8*>(&Vl[vrow_[i]][SWZ(vrow_[i], vofs_[i])]) = vreg[i];
    if (kt + 1 < ktiles) {
      const int nb = kbase + 64;
#pragma unroll
      for (int i = 0; i < 6; ++i)
        kreg[i] = *reinterpret_cast<const u16x8*>(kfh + (size_t)(nb + krow_[i]) * QKD + kofs_[i]);
#pragma unroll
      for (int i = 0; i < 4; ++i)
        vreg[i] = *reinterpret_cast<const u16x8*>(vth + (size_t)vrow_[i] * S + nb + vofs_[i]);
    }
    asm volatile("s_waitcnt lgkmcnt(0)" ::: "memory");
    __builtin_amdgcn_s_barrier();

    f32x4 sacc[4];
#pragma unroll
    for (int nf = 0; nf < 4; ++nf) sacc[nf] = {0.f, 0.f, 0.f, 0.f};
    __builtin_amdgcn_s_setprio(1);
#pragma unroll
    for (int nf = 0; nf < 4; ++nf)
#pragma unroll
      for (int dk = 0; dk < 6; ++dk) {
        int krow = nf * 16 + lr;
        bf16x8 b = *reinterpret_cast<const bf16x8*>(&Kl[krow][SWZ(krow, dk * 32 + lk * 8)]);
        sacc[nf] = __builtin_amdgcn_mfma_f32_16x16x32_bf16(qfrag[dk], b, sacc[nf], 0, 0, 0);
      }
    __builtin_amdgcn_s_setprio(0);

    float sv[4][4];
    float rowmax[4] = {-__builtin_inff(), -__builtin_inff(), -__builtin_inff(), -__builtin_inff()};
#pragma unroll
    for (int nf = 0; nf < 4; ++nf) {
      int kcol = kbase + nf * 16 + lr;
#pragma unroll
      for (int r = 0; r < 4; ++r) {
        float v = sacc[nf][r] * SCALING;
        int qrow_g = qbase + wave * 16 + lk * 4 + r;
        if (kcol > qrow_g) v = -__builtin_inff();
        sv[nf][r] = v;
        rowmax[r] = fmaxf(rowmax[r], v);
      }
    }
#pragma unroll
    for (int r = 0; r < 4; ++r) {
#pragma unroll
      for (int off = 1; off < 16; off <<= 1)
        rowmax[r] = fmaxf(rowmax[r], __shfl_xor(rowmax[r], off));
    }
    // T13 defer-max: skip rescale while per-tile max growth <= 8
    float needm = fmaxf(fmaxf(rowmax[0] - m_[0], rowmax[1] - m_[1]),
                        fmaxf(rowmax[2] - m_[2], rowmax[3] - m_[3]));
    if (!__all(needm <= 8.0f)) {
#pragma unroll
      for (int r = 0; r < 4; ++r) {
        float mn = fmaxf(m_[r], rowmax[r]);
        float alpha = __expf(m_[r] - mn);
        m_[r] = mn;
        l_[r] *= alpha;
#pragma unroll
        for (int f = 0; f < 8; ++f) o[f][r] *= alpha;
      }
    }
    float rowsum[4] = {0.f, 0.f, 0.f, 0.f};
#pragma unroll
    for (int nf = 0; nf < 4; ++nf)
#pragma unroll
      for (int r = 0; r < 4; ++r) {
        float p = __expf(sv[nf][r] - m_[r]);
        sv[nf][r] = p;
        rowsum[r] += p;
      }
#pragma unroll
    for (int r = 0; r < 4; ++r) {
#pragma unroll
      for (int off = 1; off < 16; off <<= 1) rowsum[r] += __shfl_xor(rowsum[r], off);
      l_[r] += rowsum[r];
    }
#pragma unroll
    for (int nf = 0; nf < 4; ++nf)
#pragma unroll
      for (int r = 0; r < 4; ++r) {
        int prow = lk * 4 + r;
        Pl[wave][prow][SWZ(prow, nf * 16 + lr)] = f2b(sv[nf][r]);
      }

    __builtin_amdgcn_s_setprio(1);
#pragma unroll
    for (int kk = 0; kk < 2; ++kk) {
      bf16x8 pa = *reinterpret_cast<const bf16x8*>(&Pl[wave][lr][SWZ(lr, kk * 32 + lk * 8)]);
#pragma unroll
      for (int f = 0; f < 8; ++f) {
        int vrow = f * 16 + lr;
        bf16x8 b = *reinterpret_cast<const bf16x8*>(&Vl[vrow][SWZ(vrow, kk * 32 + lk * 8)]);
        o[f] = __builtin_amdgcn_mfma_f32_16x16x32_bf16(pa, b, o[f], 0, 0, 0);
      }
    }
    __builtin_amdgcn_s_setprio(0);
  }

#pragma unroll
  for (int f = 0; f < 8; ++f)
#pragma unroll
    for (int r = 0; r < 4; ++r) {
      int row = qbase + wave * 16 + lk * 4 + r;
      float val = o[f][r] / l_[r];
      attn[(size_t)row * (H * VD) + h * VD + f * 16 + lr] = f2b(val);
    }
}

// ---------------- host launch ----------------
extern "C" void kernel_launch(void* const* d_in, const int* in_sizes, int n_in,
                              void* d_out, int out_size, void* d_ws, size_t ws_size,
                              hipStream_t stream) {
  (void)in_sizes; (void)n_in; (void)out_size; (void)ws_size;
  const float* hidden    = (const float*)d_in[1];
  const float* w_q_a     = (const float*)d_in[2];
  const float* q_a_ln_w  = (const float*)d_in[3];
  const float* w_q_b     = (const float*)d_in[4];
  const float* w_kv_a    = (const float*)d_in[5];
  const float* kv_a_ln_w = (const float*)d_in[6];
  const float* w_kv_b    = (const float*)d_in[7];
  const float* w_o       = (const float*)d_in[8];
  float* out = (float*)d_out;

  char* ws = (char*)d_ws;
  size_t off = 0;
  auto alloc = [&](size_t bytes) {
    size_t o = off;
    off += (bytes + 255) & ~(size_t)255;
    return o;
  };
  constexpr int KVA_PAD = 640;  // 576 padded to multiple of 128 (unguarded DMA)
  size_t o_hs    = alloc((size_t)S * HIDDEN * 2);        // hs bf16; later reused as qf
  size_t o_btqa  = alloc((size_t)QLORA * HIDDEN * 2);    // later (with o_btkva) bt_o
  size_t o_btkva = alloc((size_t)KVA_PAD * HIDDEN * 2);
  size_t o_btqb  = alloc((size_t)(H * QKD) * QLORA * 2);
  size_t o_btkvb = alloc((size_t)(H * 256) * KVLORA * 2);
  size_t o_qlat0 = alloc((size_t)S * QLORA * 4);         // later reused as attn
  size_t o_qlat1 = alloc((size_t)S * QLORA * 4);
  size_t o_lat0  = alloc((size_t)S * KVA_N * 4);
  size_t o_lat1  = alloc((size_t)S * KVA_N * 4);
  size_t o_qln   = alloc((size_t)S * QLORA * 2);
  size_t o_kvln  = alloc((size_t)S * KVLORA * 2);
  size_t o_kf    = alloc((size_t)H * S * QKD * 2);
  size_t o_vt    = alloc((size_t)H * VD * S * 2);
  size_t o_cs    = alloc((size_t)S * 32 * 4);
  size_t o_sn    = alloc((size_t)S * 32 * 4);

  u16* hs_bf  = (u16*)(ws + o_hs);
  u16* bt_qa  = (u16*)(ws + o_btqa);
  u16* bt_kva = (u16*)(ws + o_btkva);
  u16* bt_qb  = (u16*)(ws + o_btqb);
  u16* bt_kvb = (u16*)(ws + o_btkvb);
  float* q_lat0 = (float*)(ws + o_qlat0);
  float* q_lat1 = (float*)(ws + o_qlat1);
  float* lat0   = (float*)(ws + o_lat0);
  float* lat1   = (float*)(ws + o_lat1);
  u16* q_ln  = (u16*)(ws + o_qln);
  u16* kv_ln = (u16*)(ws + o_kvln);
  u16* kf    = (u16*)(ws + o_kf);
  u16* vt    = (u16*)(ws + o_vt);
  float* cs = (float*)(ws + o_cs);
  float* sn = (float*)(ws + o_sn);
  // aliases (lifetimes verified: source buffers dead before alias written)
  u16* qf   = (u16*)(ws + o_hs);    // hs_bf dead after dp
  u16* bt_o = (u16*)(ws + o_btqa);  // spans btqa+btkva, dead after dp
  u16* attn = (u16*)(ws + o_qlat0); // q_lat0 dead after mid

  // 1. fused prep: convert + 4 weight transposes + rope tables (27712 blocks)
  k_prep<<<dim3(27712), dim3(256), 0, stream>>>(hidden, hs_bf, w_q_a, bt_qa,
                                                w_kv_a, bt_kva, w_q_b, bt_qb,
                                                w_kv_b, bt_kvb, cs, sn);

  // 2. down-projections: split-K=2, flat 544, row-inner mapping (L2 pinning)
  k_gemm_dp<<<dim3(544), dim3(256), 0, stream>>>(hs_bf, bt_qa, bt_kva,
                                                 q_lat0, q_lat1, lat0, lat1);

  // 3. fused mid: rmsnorms + w_o transpose + kf-rope (16384 blocks)
  k_mid<<<dim3(16384), dim3(256), 0, stream>>>(q_lat0, q_lat1, q_a_ln_w, q_ln,
                                               lat0, lat1, kv_a_ln_w, kv_ln,
                                               w_o, bt_o, cs, sn, kf);

  // 4. up-projections with fused build epilogue: flat 896, row-inner mapping
  k_gemm_up<<<dim3(896), dim3(256), 0, stream>>>(q_ln, bt_qb, kv_ln, bt_kvb,
                                                 cs, sn, qf, kf, vt);

  // 5. attention: staged-LDS (R8-proven), qt-balanced grid (512 blocks)
  k_attn<<<dim3(512), dim3(256), 0, stream>>>(qf, kf, vt, attn);

  // 6. output projection: flat 640, row-inner mapping
  k_gemm_out<<<dim3(640), dim3(256), 0, stream>>>(attn, bt_o, out);
}

// Round 11
// 309.538 us; speedup vs baseline: 1.6906x; 1.0185x over previous
//
#include <hip/hip_runtime.h>
#include <math.h>

typedef unsigned short u16;
typedef unsigned int u32;
typedef __attribute__((ext_vector_type(4))) float f32x4;
typedef __attribute__((ext_vector_type(8))) unsigned short u16x8;
typedef __attribute__((ext_vector_type(4))) unsigned short u16x4;
typedef __attribute__((ext_vector_type(4))) unsigned int u32x4;
typedef __attribute__((ext_vector_type(8))) __bf16 bf16x8;

#define DEV __device__ __forceinline__

constexpr int S = 2048;
constexpr int HIDDEN = 5120;
constexpr int H = 16;
constexpr int NOPE = 128, ROPE_D = 64, VD = 128;
constexpr int QKD = NOPE + ROPE_D;  // 192
constexpr int QLORA = 1536, KVLORA = 512;
constexpr int KVA_N = KVLORA + ROPE_D;  // 576
constexpr float SCALING = 0.11472134f;

DEV u16 f2b(float f) {
  u32 u = __builtin_bit_cast(u32, f);
  u32 r = u + 0x7FFFu + ((u >> 16) & 1u);
  return (u16)(r >> 16);
}
DEV float b2f(u16 h) { return __builtin_bit_cast(float, (u32)h << 16); }

DEV void store_out(float* p, float v) { *p = v; }
DEV void store_out(u16* p, float v) { *p = f2b(v); }

DEV void gload_lds16(const u16* g, u16* l) {
  auto* gp = (const __attribute__((address_space(1))) u16*)g;
  auto* lp = (__attribute__((address_space(3))) u16*)l;
  __builtin_amdgcn_global_load_lds(gp, lp, 16, 0, 0);
}

#define SWZ(row, col) ((col) ^ (((row) & 7) << 3))

// ================= fused prep: convert + 4 transposes + rope tables ========
DEV void transpose_tile(const float* __restrict__ in, u16* __restrict__ out,
                        int R, int C, int c0, int r0, int tid, float (*tl)[33]) {
  int tx = tid & 31, ty = tid >> 5;
  for (int r = ty; r < 32; r += 8)
    tl[r][tx] = in[(size_t)(r0 + r) * C + c0 + tx];
  __syncthreads();
  for (int r = ty; r < 32; r += 8)
    out[(size_t)(c0 + r) * R + r0 + tx] = f2b(tl[tx][r]);
}

__global__ __launch_bounds__(256) void k_prep(const float* __restrict__ hidden, u16* __restrict__ hs_bf,
                                              const float* __restrict__ w_q_a, u16* __restrict__ bt_qa,
                                              const float* __restrict__ w_kv_a, u16* __restrict__ bt_kva,
                                              const float* __restrict__ w_q_b, u16* __restrict__ bt_qb,
                                              const float* __restrict__ w_kv_b, u16* __restrict__ bt_kvb,
                                              float* __restrict__ cs, float* __restrict__ sn) {
  __shared__ float tl[32][33];
  int b = blockIdx.x, tid = threadIdx.x;
  if (b < 10240) {  // convert
    int i = (b * 256 + tid) * 4;
    f32x4 v = *reinterpret_cast<const f32x4*>(hidden + i);
    u16x4 o;
    o[0] = f2b(v[0]); o[1] = f2b(v[1]); o[2] = f2b(v[2]); o[3] = f2b(v[3]);
    *reinterpret_cast<u16x4*>(hs_bf + i) = o;
    return;
  }
  b -= 10240;
  if (b < 7680) {
    transpose_tile(w_q_a, bt_qa, HIDDEN, QLORA, (b % 48) * 32, (b / 48) * 32, tid, tl);
    return;
  }
  b -= 7680;
  if (b < 2880) {
    transpose_tile(w_kv_a, bt_kva, HIDDEN, KVA_N, (b % 18) * 32, (b / 18) * 32, tid, tl);
    return;
  }
  b -= 2880;
  if (b < 4608) {
    transpose_tile(w_q_b, bt_qb, QLORA, H * QKD, (b % 96) * 32, (b / 96) * 32, tid, tl);
    return;
  }
  b -= 4608;
  if (b < 2048) {
    transpose_tile(w_kv_b, bt_kvb, KVLORA, H * 256, (b % 128) * 32, (b / 128) * 32, tid, tl);
    return;
  }
  b -= 2048;  // rope tables, b < 256
  int idx = b * 256 + tid;
  int s = idx >> 5, j = idx & 31;
  double pf = pow(10000.0, (double)j / 32.0);
  double inv_extra = 1.0 / pf;
  double inv_interp = 1.0 / (40.0 * pf);
  double twopi = 6.283185307179586476925286766559;
  double lnb2 = 2.0 * log(10000.0);
  double lowd = floor(64.0 * log(4096.0 / (32.0 * twopi)) / lnb2);
  if (lowd < 0.0) lowd = 0.0;
  double highd = ceil(64.0 * log(4096.0 / twopi) / lnb2);
  if (highd > 63.0) highd = 63.0;
  double denom = highd - lowd;
  if (denom < 0.001) denom = 0.001;
  double ramp = ((double)j - lowd) / denom;
  ramp = ramp < 0.0 ? 0.0 : (ramp > 1.0 ? 1.0 : ramp);
  float invf = (float)(inv_interp * ramp + inv_extra * (1.0 - ramp));
  float fr = (float)s * invf;
  cs[idx] = cosf(fr);
  sn[idx] = sinf(fr);
}

// ================= bf16 GEMM core: 2-deep dbuf + counted vmcnt (R4-proven) ==
DEV void gemm_core(u16* Al, u16* Bl, const u16* __restrict__ A,
                   const u16* __restrict__ BT,
                   int Kstride, int Klen, int mbase, int nbase, f32x4 (*acc)[4]) {
  const int tid = threadIdx.x;
  const int lane = tid & 63, wave = tid >> 6;
  const int wr = wave >> 1, wc = wave & 1;
  const int lr = lane & 15, lk = lane >> 4;
  const int srow = wave * 32 + (lane >> 2);
  const int skoff = (((lane & 3) ^ ((lane >> 3) & 3))) * 8;  // source swizzle
  const int swlk8 = (lk ^ ((lr >> 1) & 3)) * 8;              // read swizzle
  const u16* aptr = A + (size_t)(mbase + srow) * Kstride + skoff;
  const u16* bptr = BT + (size_t)(nbase + srow) * Kstride + skoff;
  u16* alw = Al + wave * (32 * 32);
  u16* blw = Bl + wave * (32 * 32);

  auto STAGE = [&](int b, int kk) {
    gload_lds16(aptr + kk, alw + b * 4096);
    gload_lds16(aptr + (size_t)16 * Kstride + kk, alw + b * 4096 + 16 * 32);
    gload_lds16(bptr + kk, blw + b * 4096);
    gload_lds16(bptr + (size_t)16 * Kstride + kk, blw + b * 4096 + 16 * 32);
  };

#pragma unroll
  for (int mf = 0; mf < 4; ++mf)
#pragma unroll
    for (int nf = 0; nf < 4; ++nf) acc[mf][nf] = {0.f, 0.f, 0.f, 0.f};

  const int nt = Klen >> 5;
  STAGE(0, 0);
  STAGE(1, 32);
  for (int t = 0; t < nt; ++t) {
    const int cur = t & 1;
    if (t + 1 < nt)
      asm volatile("s_waitcnt vmcnt(4)" ::: "memory");
    else
      asm volatile("s_waitcnt vmcnt(0)" ::: "memory");
    __builtin_amdgcn_s_barrier();
    const u16* Ac = Al + cur * 4096;
    const u16* Bc = Bl + cur * 4096;
    bf16x8 af[4], bfr[4];
#pragma unroll
    for (int mf = 0; mf < 4; ++mf)
      af[mf] = *reinterpret_cast<const bf16x8*>(Ac + (wr * 64 + mf * 16 + lr) * 32 + swlk8);
#pragma unroll
    for (int nf = 0; nf < 4; ++nf)
      bfr[nf] = *reinterpret_cast<const bf16x8*>(Bc + (wc * 64 + nf * 16 + lr) * 32 + swlk8);
#pragma unroll
    for (int mf = 0; mf < 4; ++mf)
#pragma unroll
      for (int nf = 0; nf < 4; ++nf)
        acc[mf][nf] = __builtin_amdgcn_mfma_f32_16x16x32_bf16(af[mf], bfr[nf], acc[mf][nf], 0, 0, 0);
    __builtin_amdgcn_s_barrier();
    if (t + 2 < nt) STAGE(cur, (t + 2) * 32);
  }
}

template <typename OutT>
DEV void gemm_epilogue(f32x4 (*acc)[4], OutT* __restrict__ C, int N, int mbase, int nbase) {
  const int lane = threadIdx.x & 63, wave = threadIdx.x >> 6;
  const int wr = wave >> 1, wc = wave & 1;
  const int lr = lane & 15, lk = lane >> 4;
#pragma unroll
  for (int mf = 0; mf < 4; ++mf)
#pragma unroll
    for (int nf = 0; nf < 4; ++nf) {
      int col = nbase + wc * 64 + nf * 16 + lr;
      if (col < N) {
#pragma unroll
        for (int r = 0; r < 4; ++r) {
          int row = mbase + wr * 64 + mf * 16 + lk * 4 + r;
          store_out(&C[(size_t)row * N + col], acc[mf][nf][r]);
        }
      }
    }
}

// out-proj: flat 640 = 40 cols x 16 rows, row inner (XCD keeps its A rows in L2)
__global__ __launch_bounds__(256) void k_gemm_out(const u16* __restrict__ A,
                                                  const u16* __restrict__ BT,
                                                  float* __restrict__ C) {
  __shared__ u16 Al[2 * 128 * 32];
  __shared__ u16 Bl[2 * 128 * 32];
  int id = blockIdx.x;
  int row = id & 15, col = id >> 4;
  f32x4 acc[4][4];
  gemm_core(Al, Bl, A, BT, H * VD, H * VD, row * 128, col * 128, acc);
  gemm_epilogue(acc, C, HIDDEN, row * 128, col * 128);
}

// up-proj with fused epilogue: writes qf (+RoPE), kf-nope, vt directly.
// flat 896 = 56 cols x 16 rows, row inner; col<24 -> q, else kv.
__global__ __launch_bounds__(256) void k_gemm_up(const u16* __restrict__ Aq, const u16* __restrict__ Bq,
                                                 const u16* __restrict__ Akv, const u16* __restrict__ Bkv,
                                                 const float* __restrict__ cs, const float* __restrict__ sn,
                                                 u16* __restrict__ qf, u16* __restrict__ kf,
                                                 u16* __restrict__ vt) {
  __shared__ u16 Al[2 * 128 * 32];
  __shared__ u16 Bl[2 * 128 * 32];
  int id = blockIdx.x;
  int rowb = id & 15, col = id >> 4;  // col 0..55
  const int mbase = rowb * 128;
  const int lane = threadIdx.x & 63, wave = threadIdx.x >> 6;
  const int wr = wave >> 1, wc = wave & 1;
  const int lr = lane & 15, lk = lane >> 4;
  f32x4 acc[4][4];
  if (col < 24) {
    const int nbase = col * 128;
    gemm_core(Al, Bl, Aq, Bq, QLORA, QLORA, mbase, nbase, acc);
#pragma unroll
    for (int nf = 0; nf < 4; ++nf) {
      int colb = nbase + wc * 64 + nf * 16;        // frag-uniform
      int h = colb / 192;
      int db = colb - h * 192;
      size_t qoff = (size_t)h * S * QKD;
      if (db < NOPE) {
#pragma unroll
        for (int mf = 0; mf < 4; ++mf)
#pragma unroll
          for (int r = 0; r < 4; ++r) {
            int row = mbase + wr * 64 + mf * 16 + lk * 4 + r;
            qf[qoff + (size_t)row * QKD + db + lr] = f2b(acc[mf][nf][r]);
          }
      } else {  // rope cols: pair exchange via shfl_xor(1)
        int jj = (db - NOPE + lr) >> 1;
        bool odd = lr & 1;
#pragma unroll
        for (int mf = 0; mf < 4; ++mf)
#pragma unroll
          for (int r = 0; r < 4; ++r) {
            int row = mbase + wr * 64 + mf * 16 + lk * 4 + r;
            float val = acc[mf][nf][r];
            float part = __shfl_xor(val, 1);
            float c = cs[row * 32 + jj], s = sn[row * 32 + jj];
            float o = odd ? (val * c + part * s) : (val * c - part * s);
            qf[qoff + (size_t)row * QKD + db + lr] = f2b(o);
          }
      }
    }
  } else {
    const int nbase = (col - 24) * 128;
    gemm_core(Al, Bl, Akv, Bkv, KVLORA, KVLORA, mbase, nbase, acc);
#pragma unroll
    for (int nf = 0; nf < 4; ++nf) {
      int colb = nbase + wc * 64 + nf * 16;
      int h = colb >> 8;        // /256, frag-uniform
      int db = colb & 255;
      if (db < NOPE) {          // k_nope -> kf
        size_t koff = (size_t)h * S * QKD;
#pragma unroll
        for (int mf = 0; mf < 4; ++mf)
#pragma unroll
          for (int r = 0; r < 4; ++r) {
            int row = mbase + wr * 64 + mf * 16 + lk * 4 + r;
            kf[koff + (size_t)row * QKD + db + lr] = f2b(acc[mf][nf][r]);
          }
      } else {                  // v -> vt (free transpose: frag is col-major)
        int vtrow = h * VD + db - NOPE + lr;
#pragma unroll
        for (int mf = 0; mf < 4; ++mf) {
          int row0 = mbase + wr * 64 + mf * 16 + lk * 4;
          u16x4 pk;
          pk[0] = f2b(acc[mf][nf][0]); pk[1] = f2b(acc[mf][nf][1]);
          pk[2] = f2b(acc[mf][nf][2]); pk[3] = f2b(acc[mf][nf][3]);
          *reinterpret_cast<u16x4*>(&vt[(size_t)vtrow * S + row0]) = pk;
        }
      }
    }
  }
}

// down-proj, split-K=2: flat 544 = 2 splits x 17 cols x 16 rows, row inner.
__global__ __launch_bounds__(256) void k_gemm_dp(const u16* __restrict__ A,
                                                 const u16* __restrict__ Bq,
                                                 const u16* __restrict__ Bkv,
                                                 float* __restrict__ q0, float* __restrict__ q1,
                                                 float* __restrict__ l0, float* __restrict__ l1) {
  __shared__ u16 Al[2 * 128 * 32];
  __shared__ u16 Bl[2 * 128 * 32];
  constexpr int KH = HIDDEN / 2;  // 2560
  int id = blockIdx.x;
  int split = id >= 272;
  int u = id - split * 272;
  int row = u & 15, colt = u >> 4;  // colt 0..16
  const u16* As = A + split * KH;
  f32x4 acc[4][4];
  if (colt < 12) {
    gemm_core(Al, Bl, As, Bq + split * KH, HIDDEN, KH, row * 128, colt * 128, acc);
    gemm_epilogue(acc, split ? q1 : q0, QLORA, row * 128, colt * 128);
  } else {
    gemm_core(Al, Bl, As, Bkv + split * KH, HIDDEN, KH, row * 128, (colt - 12) * 128, acc);
    gemm_epilogue(acc, split ? l1 : l0, KVA_N, row * 128, (colt - 12) * 128);
  }
}

// ====== fused mid: 2x rmsnorm(split-K reduce) + w_o transpose + kf-rope =====
DEV void rmsnorm2_row(const float* __restrict__ x0, const float* __restrict__ x1,
                      const float* __restrict__ w, u16* __restrict__ y,
                      int ncols, int instride, int row, int tid, float* red) {
  const float* xr0 = x0 + (size_t)row * instride;
  const float* xr1 = x1 + (size_t)row * instride;
  float ss = 0.f;
  for (int i = tid * 4; i < ncols; i += 1024) {
    f32x4 a = *reinterpret_cast<const f32x4*>(xr0 + i);
    f32x4 b = *reinterpret_cast<const f32x4*>(xr1 + i);
    f32x4 v = a + b;
    ss += v[0] * v[0] + v[1] * v[1] + v[2] * v[2] + v[3] * v[3];
  }
  for (int off = 32; off > 0; off >>= 1) ss += __shfl_down(ss, off);
  if ((tid & 63) == 0) red[tid >> 6] = ss;
  __syncthreads();
  ss = red[0] + red[1] + red[2] + red[3];
  float sc = rsqrtf(ss / (float)ncols + 1e-6f);
  u16* yr = y + (size_t)row * ncols;
  for (int i = tid * 4; i < ncols; i += 1024) {
    f32x4 a = *reinterpret_cast<const f32x4*>(xr0 + i);
    f32x4 b = *reinterpret_cast<const f32x4*>(xr1 + i);
    f32x4 v = a + b;
    u16x4 o;
    o[0] = f2b(v[0] * sc * w[i]);
    o[1] = f2b(v[1] * sc * w[i + 1]);
    o[2] = f2b(v[2] * sc * w[i + 2]);
    o[3] = f2b(v[3] * sc * w[i + 3]);
    *reinterpret_cast<u16x4*>(yr + i) = o;
  }
}

__global__ __launch_bounds__(256) void k_mid(const float* __restrict__ q0, const float* __restrict__ q1,
                                             const float* __restrict__ qw, u16* __restrict__ q_ln,
                                             const float* __restrict__ l0, const float* __restrict__ l1,
                                             const float* __restrict__ kw, u16* __restrict__ kv_ln,
                                             const float* __restrict__ w_o, u16* __restrict__ bt_o,
                                             const float* __restrict__ cs, const float* __restrict__ sn,
                                             u16* __restrict__ kf) {
  __shared__ float red[4];
  __shared__ float tl[32][33];
  int b = blockIdx.x, tid = threadIdx.x;
  if (b < 2048) {
    rmsnorm2_row(q0, q1, qw, q_ln, QLORA, QLORA, b, tid, red);
    return;
  }
  if (b < 4096) {
    rmsnorm2_row(l0, l1, kw, kv_ln, KVLORA, KVA_N, b - 2048, tid, red);
    return;
  }
  if (b < 14336) {
    int u = b - 4096;  // w_o transpose: R=2048, C=5120, 160x64 tiles
    transpose_tile(w_o, bt_o, H * VD, HIDDEN, (u % 160) * 32, (u / 160) * 32, tid, tl);
    return;
  }
  // kf-rope: k_pe from latent, broadcast to all heads.  b in [14336, 16384)
  int s = b - 14336;
  for (int idx = tid; idx < H * 32; idx += 256) {
    int h = idx >> 5, j = idx & 31;
    float c = cs[s * 32 + j], si = sn[s * 32 + j];
    float k1 = l0[(size_t)s * KVA_N + KVLORA + 2 * j] + l1[(size_t)s * KVA_N + KVLORA + 2 * j];
    float k2 = l0[(size_t)s * KVA_N + KVLORA + 2 * j + 1] + l1[(size_t)s * KVA_N + KVLORA + 2 * j + 1];
    kf[((size_t)h * S + s) * QKD + NOPE + 2 * j] = f2b(k1 * c - k2 * si);
    kf[((size_t)h * S + s) * QKD + NOPE + 2 * j + 1] = f2b(k2 * c + k1 * si);
  }
}

// ===== flash attention (causal): swapped-operand, in-register softmax =======
// mfma(K,Q) -> lane owns q-row (q = lane&15); softmax state lane-local.
// PV as mfma(V^T, P^T): P repacked in-register (no P LDS round-trip).
// grid 512 flat; blocks i and i+256 get complementary qt (work-balanced).
__global__ __launch_bounds__(256) void k_attn(const u16* __restrict__ qf,
                                              const u16* __restrict__ kf,
                                              const u16* __restrict__ vt,
                                              u16* __restrict__ attn) {
  const int bidx = blockIdx.x;
  const int j = bidx & 31;
  const int h = bidx >> 5;
  const int qt = (h < 8) ? j : 31 - j;
  const int qbase = qt * 64;
  const int tid = threadIdx.x, wave = tid >> 6, lane = tid & 63;
  const int lr = lane & 15, lk = lane >> 4;
  __shared__ u16 Kl[64][192];
  __shared__ u16 Vl[128][64];

  int krow_[6], kofs_[6], vrow_[4], vofs_[4];
#pragma unroll
  for (int i = 0; i < 6; ++i) { int c = tid + i * 256; krow_[i] = c / 24; kofs_[i] = (c % 24) * 8; }
#pragma unroll
  for (int i = 0; i < 4; ++i) { int c = tid + i * 256; vrow_[i] = c >> 3; vofs_[i] = (c & 7) * 8; }
  const u16* kfh = kf + (size_t)h * S * QKD;
  const u16* vth = vt + (size_t)h * VD * S;

  // Q as B-operand: lane holds q-col (lr), d-slice lk*8 (same bytes as A-frag)
  bf16x8 qfrag[6];
  const u16* qrow = qf + ((size_t)h * S + qbase + wave * 16 + lr) * QKD;
#pragma unroll
  for (int d = 0; d < 6; ++d)
    qfrag[d] = *reinterpret_cast<const bf16x8*>(qrow + d * 32 + lk * 8);

  u16x8 kreg[6], vreg[4];
#pragma unroll
  for (int i = 0; i < 6; ++i)
    kreg[i] = *reinterpret_cast<const u16x8*>(kfh + (size_t)krow_[i] * QKD + kofs_[i]);
#pragma unroll
  for (int i = 0; i < 4; ++i)
    vreg[i] = *reinterpret_cast<const u16x8*>(vth + (size_t)vrow_[i] * S + vofs_[i]);

  // o[f][r] = O[q = qbase+wave*16+lr][vd = f*16 + 4*lk + r]
  f32x4 o[8];
#pragma unroll
  for (int f = 0; f < 8; ++f) o[f] = {0.f, 0.f, 0.f, 0.f};
  float m_ = -__builtin_inff();  // per-lane: q-row lr of this wave
  float l_ = 0.f;
  const int qrow_g = qbase + wave * 16 + lr;

  const int ktiles = qt + 1;
  for (int kt = 0; kt < ktiles; ++kt) {
    const int kbase = kt * 64;
    __builtin_amdgcn_s_barrier();
#pragma unroll
    for (int i = 0; i < 6; ++i)
      *reinterpret_cast<u16x8*>(&Kl[krow_[i]][SWZ(krow_[i], kofs_[i])]) = kreg[i];
#pragma unroll
    for (int i = 0; i < 4; ++i)
      *reinterpret_cast<u16x8*>(&Vl[vrow_[i]][SWZ(vrow_[i], vofs_[i])]) = vreg[i];
    if (kt + 1 < ktiles) {
      const int nb = kbase + 64;
#pragma unroll
      for (int i = 0; i < 6; ++i)
        kreg[i] = *reinterpret_cast<const u16x8*>(kfh + (size_t)(nb + krow_[i]) * QKD + kofs_[i]);
#pragma unroll
      for (int i = 0; i < 4; ++i)
        vreg[i] = *reinterpret_cast<const u16x8*>(vth + (size_t)vrow_[i] * S + nb + vofs_[i]);
    }
    asm volatile("s_waitcnt lgkmcnt(0)" ::: "memory");
    __builtin_amdgcn_s_barrier();

    // QK^T swapped: sacc[nf][r] = S[k = kbase+nf*16+lk*4+r][q = lr]
    f32x4 sacc[4];
#pragma unroll
    for (int nf = 0; nf < 4; ++nf) sacc[nf] = {0.f, 0.f, 0.f, 0.f};
    __builtin_amdgcn_s_setprio(1);
#pragma unroll
    for (int nf = 0; nf < 4; ++nf)
#pragma unroll
      for (int dk = 0; dk < 6; ++dk) {
        int krow = nf * 16 + lr;
        bf16x8 a = *reinterpret_cast<const bf16x8*>(&Kl[krow][SWZ(krow, dk * 32 + lk * 8)]);
        sacc[nf] = __builtin_amdgcn_mfma_f32_16x16x32_bf16(a, qfrag[dk], sacc[nf], 0, 0, 0);
      }
    __builtin_amdgcn_s_setprio(0);

    // scale + causal mask (lane-local q-row), lane-local softmax
    float p[4][4];
    float rowmax = -__builtin_inff();
#pragma unroll
    for (int nf = 0; nf < 4; ++nf)
#pragma unroll
      for (int r = 0; r < 4; ++r) {
        float v = sacc[nf][r] * SCALING;
        int kcol = kbase + nf * 16 + lk * 4 + r;
        if (kcol > qrow_g) v = -__builtin_inff();
        p[nf][r] = v;
        rowmax = fmaxf(rowmax, v);
      }
    // reduce across the 4 lk-groups only (q-row is lane-local)
    rowmax = fmaxf(rowmax, __shfl_xor(rowmax, 16));
    rowmax = fmaxf(rowmax, __shfl_xor(rowmax, 32));

    // T13 defer-max
    if (!__all(rowmax - m_ <= 8.0f)) {
      float mn = fmaxf(m_, rowmax);
      float alpha = __expf(m_ - mn);
      m_ = mn;
      l_ *= alpha;
#pragma unroll
      for (int f = 0; f < 8; ++f)
#pragma unroll
        for (int r = 0; r < 4; ++r) o[f][r] *= alpha;
    }
    float rowsum = 0.f;
#pragma unroll
    for (int nf = 0; nf < 4; ++nf)
#pragma unroll
      for (int r = 0; r < 4; ++r) {
        float e = __expf(p[nf][r] - m_);
        p[nf][r] = e;
        rowsum += e;
      }
    rowsum += __shfl_xor(rowsum, 16);
    rowsum += __shfl_xor(rowsum, 32);
    l_ += rowsum;

    // pack P to bf16 pairs: P2[nf][w] = pack(p[nf][2w], p[nf][2w+1])
    u32 P2[4][2];
#pragma unroll
    for (int nf = 0; nf < 4; ++nf) {
#pragma unroll
      for (int w = 0; w < 2; ++w)
        P2[nf][w] = (u32)f2b(p[nf][2 * w]) | ((u32)f2b(p[nf][2 * w + 1]) << 16);
    }

    // PV swapped: o = mfma(V^T-frag, P^T-frag, o) per kk subtile.
    // B-frag (P^T) at lane (lr,lk): P[q=lr][k = 32kk + 8lk + 0..8],
    // gathered from lanes lr + 32*(lk&1) (+16) via register shuffles.
    const int srcA = lr + 32 * (lk & 1);
    const int srcB = srcA + 16;
    const bool lo = (lk < 2);
    __builtin_amdgcn_s_setprio(1);
#pragma unroll
    for (int kk = 0; kk < 2; ++kk) {
      u32 a0 = __shfl((int)P2[2 * kk][0], srcA), a1 = __shfl((int)P2[2 * kk][1], srcA);
      u32 a2 = __shfl((int)P2[2 * kk][0], srcB), a3 = __shfl((int)P2[2 * kk][1], srcB);
      u32 b0 = __shfl((int)P2[2 * kk + 1][0], srcA), b1 = __shfl((int)P2[2 * kk + 1][1], srcA);
      u32 b2 = __shfl((int)P2[2 * kk + 1][0], srcB), b3 = __shfl((int)P2[2 * kk + 1][1], srcB);
      u32x4 wsel;
      wsel[0] = lo ? a0 : b0; wsel[1] = lo ? a1 : b1;
      wsel[2] = lo ? a2 : b2; wsel[3] = lo ? a3 : b3;
      bf16x8 pvB = __builtin_bit_cast(bf16x8, wsel);
#pragma unroll
      for (int f = 0; f < 8; ++f) {
        int vrow = f * 16 + lr;
        bf16x8 a = *reinterpret_cast<const bf16x8*>(&Vl[vrow][SWZ(vrow, kk * 32 + lk * 8)]);
        o[f] = __builtin_amdgcn_mfma_f32_16x16x32_bf16(a, pvB, o[f], 0, 0, 0);
      }
    }
    __builtin_amdgcn_s_setprio(0);
  }

  // epilogue: normalize and store (4 consecutive vd per u16x4)
  float inv_l = 1.0f / l_;
#pragma unroll
  for (int f = 0; f < 8; ++f) {
    u16x4 pk;
#pragma unroll
    for (int r = 0; r < 4; ++r) pk[r] = f2b(o[f][r] * inv_l);
    *reinterpret_cast<u16x4*>(&attn[(size_t)qrow_g * (H * VD) + h * VD + f * 16 + 4 * lk]) = pk;
  }
}

// ---------------- host launch ----------------
extern "C" void kernel_launch(void* const* d_in, const int* in_sizes, int n_in,
                              void* d_out, int out_size, void* d_ws, size_t ws_size,
                              hipStream_t stream) {
  (void)in_sizes; (void)n_in; (void)out_size; (void)ws_size;
  const float* hidden    = (const float*)d_in[1];
  const float* w_q_a     = (const float*)d_in[2];
  const float* q_a_ln_w  = (const float*)d_in[3];
  const float* w_q_b     = (const float*)d_in[4];
  const float* w_kv_a    = (const float*)d_in[5];
  const float* kv_a_ln_w = (const float*)d_in[6];
  const float* w_kv_b    = (const float*)d_in[7];
  const float* w_o       = (const float*)d_in[8];
  float* out = (float*)d_out;

  char* ws = (char*)d_ws;
  size_t off = 0;
  auto alloc = [&](size_t bytes) {
    size_t o = off;
    off += (bytes + 255) & ~(size_t)255;
    return o;
  };
  constexpr int KVA_PAD = 640;  // 576 padded to multiple of 128 (unguarded DMA)
  size_t o_hs    = alloc((size_t)S * HIDDEN * 2);        // hs bf16; later reused as qf
  size_t o_btqa  = alloc((size_t)QLORA * HIDDEN * 2);    // later (with o_btkva) bt_o
  size_t o_btkva = alloc((size_t)KVA_PAD * HIDDEN * 2);
  size_t o_btqb  = alloc((size_t)(H * QKD) * QLORA * 2);
  size_t o_btkvb = alloc((size_t)(H * 256) * KVLORA * 2);
  size_t o_qlat0 = alloc((size_t)S * QLORA * 4);         // later reused as attn
  size_t o_qlat1 = alloc((size_t)S * QLORA * 4);
  size_t o_lat0  = alloc((size_t)S * KVA_N * 4);
  size_t o_lat1  = alloc((size_t)S * KVA_N * 4);
  size_t o_qln   = alloc((size_t)S * QLORA * 2);
  size_t o_kvln  = alloc((size_t)S * KVLORA * 2);
  size_t o_kf    = alloc((size_t)H * S * QKD * 2);
  size_t o_vt    = alloc((size_t)H * VD * S * 2);
  size_t o_cs    = alloc((size_t)S * 32 * 4);
  size_t o_sn    = alloc((size_t)S * 32 * 4);

  u16* hs_bf  = (u16*)(ws + o_hs);
  u16* bt_qa  = (u16*)(ws + o_btqa);
  u16* bt_kva = (u16*)(ws + o_btkva);
  u16* bt_qb  = (u16*)(ws + o_btqb);
  u16* bt_kvb = (u16*)(ws + o_btkvb);
  float* q_lat0 = (float*)(ws + o_qlat0);
  float* q_lat1 = (float*)(ws + o_qlat1);
  float* lat0   = (float*)(ws + o_lat0);
  float* lat1   = (float*)(ws + o_lat1);
  u16* q_ln  = (u16*)(ws + o_qln);
  u16* kv_ln = (u16*)(ws + o_kvln);
  u16* kf    = (u16*)(ws + o_kf);
  u16* vt    = (u16*)(ws + o_vt);
  float* cs = (float*)(ws + o_cs);
  float* sn = (float*)(ws + o_sn);
  // aliases (lifetimes verified: source buffers dead before alias written)
  u16* qf   = (u16*)(ws + o_hs);    // hs_bf dead after dp
  u16* bt_o = (u16*)(ws + o_btqa);  // spans btqa+btkva, dead after dp
  u16* attn = (u16*)(ws + o_qlat0); // q_lat0 dead after mid

  // 1. fused prep: convert + 4 weight transposes + rope tables (27712 blocks)
  k_prep<<<dim3(27712), dim3(256), 0, stream>>>(hidden, hs_bf, w_q_a, bt_qa,
                                                w_kv_a, bt_kva, w_q_b, bt_qb,
                                                w_kv_b, bt_kvb, cs, sn);

  // 2. down-projections: split-K=2, flat 544, row-inner mapping (L2 pinning)
  k_gemm_dp<<<dim3(544), dim3(256), 0, stream>>>(hs_bf, bt_qa, bt_kva,
                                                 q_lat0, q_lat1, lat0, lat1);

  // 3. fused mid: rmsnorms + w_o transpose + kf-rope (16384 blocks)
  k_mid<<<dim3(16384), dim3(256), 0, stream>>>(q_lat0, q_lat1, q_a_ln_w, q_ln,
                                               lat0, lat1, kv_a_ln_w, kv_ln,
                                               w_o, bt_o, cs, sn, kf);

  // 4. up-projections with fused build epilogue: flat 896, row-inner mapping
  k_gemm_up<<<dim3(896), dim3(256), 0, stream>>>(q_ln, bt_qb, kv_ln, bt_kvb,
                                                 cs, sn, qf, kf, vt);

  // 5. attention: swapped-operand in-register softmax (512 blocks)
  k_attn<<<dim3(512), dim3(256), 0, stream>>>(qf, kf, vt, attn);

  // 6. output projection: flat 640, row-inner mapping
  k_gemm_out<<<dim3(640), dim3(256), 0, stream>>>(attn, bt_o, out);
}